// Round 8
// baseline (261.863 us; speedup 1.0000x reference)
//
#include <hip/hip_runtime.h>

typedef __attribute__((ext_vector_type(8))) short short8;
typedef __attribute__((ext_vector_type(4))) float f32x4;
typedef __attribute__((ext_vector_type(4))) unsigned short u16x4;
typedef __attribute__((ext_vector_type(2))) unsigned int u32x2;

#define MFMA16(a,b,c) __builtin_amdgcn_mfma_f32_16x16x32_bf16((a),(b),(c),0,0,0)

// 0.125 (attn scale) * log2(e), folded into Q at the QKV epilogue.
#define QSCALE 0.1803368801f

__device__ __forceinline__ unsigned short f2bf(float f) {
  unsigned int x = __float_as_uint(f);
  x += 0x7fffu + ((x >> 16) & 1u);
  return (unsigned short)(x >> 16);
}
__device__ __forceinline__ unsigned int pack2bf(float a, float b) {
  unsigned int ua = __float_as_uint(a) + 0x8000u;
  unsigned int ub = __float_as_uint(b) + 0x8000u;
  return __builtin_amdgcn_perm(ub, ua, 0x07060302);
}
// async 16B global -> LDS (dest = wave-uniform base + lane*16)
__device__ __forceinline__ void gload16(const unsigned short* g, unsigned short* l) {
  __builtin_amdgcn_global_load_lds(
      (const __attribute__((address_space(1))) unsigned int*)g,
      (__attribute__((address_space(3))) unsigned int*)l, 16, 0, 0);
}

// ---------------------------------------------------------------------------
// Kernel 1: prep = convert_x (blocks < 6144) + build_weights (rest).
// ---------------------------------------------------------------------------
__global__ __launch_bounds__(256) void prep(
    const float* __restrict__ x,
    const float* __restrict__ w_qkv,
    const float* __restrict__ w_proj,
    const float* __restrict__ q_a, const float* __restrict__ q_b,
    const float* __restrict__ k_a, const float* __restrict__ k_b,
    const float* __restrict__ v_a, const float* __restrict__ v_b,
    const float* __restrict__ o_a, const float* __restrict__ o_b,
    unsigned short* __restrict__ xb,
    unsigned short* __restrict__ wqkv_eff,
    unsigned short* __restrict__ wproj_eff)
{
  int bid = blockIdx.x;
  if (bid < 6144) {
    int i4 = (bid * 256 + threadIdx.x) * 4;
    f32x4 v = *(const f32x4*)&x[i4];
    u16x4 o;
    o.x = f2bf(v.x); o.y = f2bf(v.y); o.z = f2bf(v.z); o.w = f2bf(v.w);
    *(u16x4*)&xb[i4] = o;
    return;
  }
  const int QKV = 2304 * 768;
  int idx = (bid - 6144) * 256 + threadIdx.x;
  if (idx < QKV) {
    int n = idx / 768, c = idx - n * 768;
    int sec = n / 768;
    int nr = n - sec * 768;
    const float* a; const float* b;
    if (sec == 0)      { a = q_a; b = q_b; }
    else if (sec == 1) { a = k_a; b = k_b; }
    else               { a = v_a; b = v_b; }
    float acc = w_qkv[idx];
    #pragma unroll
    for (int r = 0; r < 8; r++)
      acc += b[nr * 8 + r] * a[r * 768 + c];
    wqkv_eff[idx] = f2bf(acc);
  } else {
    int i2 = idx - QKV;
    int n = i2 / 768, c = i2 - n * 768;
    float acc = w_proj[i2];
    #pragma unroll
    for (int r = 0; r < 8; r++)
      acc += o_b[n * 8 + r] * o_a[r * 768 + c];
    wproj_eff[i2] = f2bf(acc);
  }
}

// ---------------------------------------------------------------------------
// Kernel 2/4: C[M,N'] = A[M,K] @ W[N',K]^T + bias. 1-barrier K-loop:
//  - A frags: direct global->register, loaded in-iteration (single set, 32
//    VGPRs; each 16B chunk owned by exactly one lane -> LDS staging for A is
//    pure overhead). Issued BEFORE W staging so the FIFO vmcnt wait for A
//    (vmcnt(4)) doesn't drain the younger W-staging loads.
//  - W: double-buffered LDS (2x16KB) via async global_load_lds(16B); stage
//    (k+1 -> buf 1-p) after the barrier, compute from buf p. Pre-barrier
//    vmcnt(0) drain covers staging that had a full compute phase in flight.
// LDS 32KB (was 64KB in R7 -> residency doubles). XOR swizzle (0 conflicts,
// R5-verified). 128x128 tile, BK=64, 2x2 wave grid, 64x64 out/wave.
// Requires K/64 even.
// mode 0 (QKV): Q*QSCALE -> q[BH][N][64]; K -> k[BH][N][64];
//               V -> vt[BH][64][1024], key-permuted cols (4*(np&15)+((np>>4)&3)).
// mode 1: fp32 row-major store (final output).
// ---------------------------------------------------------------------------
#define GSTEP(kk, p)                                                          \
  {                                                                           \
    __syncthreads();                                                          \
    const int k0_ = (kk) << 6;                                                \
    const int kn_ = ((kk) + 1) << 6;                                          \
    short8 a_[4][2];                                                          \
    _Pragma("unroll")                                                         \
    for (int t = 0; t < 4; t++) {                                             \
      a_[t][0] = *(const short8*)&gA[t][k0_];                                 \
      a_[t][1] = *(const short8*)&gA[t][k0_ + 32];                            \
    }                                                                         \
    if (kn_ < K) {                                                            \
      _Pragma("unroll")                                                       \
      for (int t = 0; t < 4; t++)                                             \
        gload16(gW[t] + kn_, &Ws2[1 - (p)][ls_off[t]]);                       \
    }                                                                         \
    _Pragma("unroll")                                                         \
    for (int ks = 0; ks < 2; ks++) {                                          \
      const int cs = ks * 4 + quad;                                           \
      short8 b_[4];                                                           \
      _Pragma("unroll")                                                       \
      for (int t = 0; t < 4; t++)                                             \
        b_[t] = *(const short8*)&Ws2[p][(wc * 64 + t * 16 + l16) * 64 +       \
                                        ((cs ^ swz) << 3)];                   \
      _Pragma("unroll")                                                       \
      for (int i = 0; i < 4; i++)                                             \
        _Pragma("unroll")                                                     \
        for (int j = 0; j < 4; j++)                                           \
          acc[i][j] = MFMA16(a_[i][ks], b_[j], acc[i][j]);                    \
    }                                                                         \
  }

__global__ __launch_bounds__(256) void gemm_bt(
    const unsigned short* __restrict__ A,
    const unsigned short* __restrict__ W,
    const float* __restrict__ bias,
    unsigned short* __restrict__ out0,
    unsigned short* __restrict__ out1,
    unsigned short* __restrict__ out2,
    float* __restrict__ outf,
    int K, int Ncols, int mode)
{
  __shared__ alignas(16) unsigned short Ws2[2][128 * 64];  // 2 x 16 KB
  const int tid  = threadIdx.x;
  const int wave = tid >> 6;
  const int lane = tid & 63;
  const int quad = lane >> 4;
  const int l16  = lane & 15;
  const int wr   = wave >> 1, wc = wave & 1;   // 2x2 wave grid
  const int m0 = blockIdx.x * 128;
  const int n0 = blockIdx.y * 128;
  const int swz = l16 & 7;

  // W staging: wave stages rows [wave*32, +32); lane -> row +(lane>>3),
  // global chunk (lane&7)^(row&7), LDS slot (lane&7) (= HW base+lane*16).
  const int lrow   = lane >> 3;
  const int lchunk = (lane & 7) ^ lrow;
  const unsigned short* gW[4];
  int ls_off[4];
  #pragma unroll
  for (int t = 0; t < 4; t++) {
    int rr = wave * 32 + t * 8;
    gW[t]     = W + (size_t)(n0 + rr + lrow) * K + lchunk * 8;
    ls_off[t] = (rr + lrow) * 64 + (lane & 7) * 8;
  }
  // A direct-to-register: frag(t,ks) = 16B at row m0+wr*64+t*16+l16,
  // col k0+ks*32+quad*8.
  const unsigned short* gA[4];
  #pragma unroll
  for (int t = 0; t < 4; t++)
    gA[t] = A + (size_t)(m0 + wr * 64 + t * 16 + l16) * K + quad * 8;

  f32x4 acc[4][4] = {};

  // prologue: stage W(0) into buf 0
  #pragma unroll
  for (int t = 0; t < 4; t++) gload16(gW[t], &Ws2[0][ls_off[t]]);

  const int nit = K >> 6;                      // even (768/64 = 12)
  for (int k = 0; k < nit; k += 2) {
    GSTEP(k,     0);
    GSTEP(k + 1, 1);
  }

  float bv[4];
  #pragma unroll
  for (int j = 0; j < 4; j++) bv[j] = bias[n0 + wc * 64 + j * 16 + l16];

  if (mode == 0) {
    const int sec = n0 / 768;                       // uniform (768 % 128 == 0)
    const int h   = ((n0 % 768) >> 6) + wc;         // wave's head
    unsigned short* dst = (sec == 0) ? out0 : ((sec == 1) ? out1 : out2);
    const float scl = (sec == 0) ? QSCALE : 1.0f;
    #pragma unroll
    for (int i = 0; i < 4; i++) {
      #pragma unroll
      for (int r = 0; r < 4; r++) {
        int m  = m0 + wr * 64 + i * 16 + quad * 4 + r;
        int bb = m >> 10, np = m & 1023;
        int bh = bb * 12 + h;
        int npp = (np & ~63) | ((np & 15) * 4 + ((np >> 4) & 3)); // key perm
        #pragma unroll
        for (int j = 0; j < 4; j++) {
          int d = j * 16 + l16;
          float v = (acc[i][j][r] + bv[j]) * scl;
          if (sec < 2) dst[((size_t)bh << 16) + ((size_t)np << 6) + d] = f2bf(v);
          else         dst[((size_t)bh << 16) + ((size_t)d << 10) + npp] = f2bf(v);
        }
      }
    }
  } else {
    #pragma unroll
    for (int i = 0; i < 4; i++) {
      #pragma unroll
      for (int r = 0; r < 4; r++) {
        int m = m0 + wr * 64 + i * 16 + quad * 4 + r;
        #pragma unroll
        for (int j = 0; j < 4; j++)
          outf[(size_t)m * Ncols + n0 + wc * 64 + j * 16 + l16] = acc[i][j][r] + bv[j];
      }
    }
  }
}

// ---------------------------------------------------------------------------
// Kernel 3: flash attention (unchanged).
// ---------------------------------------------------------------------------
__global__ __launch_bounds__(256) void attn(
    const unsigned short* __restrict__ q,
    const unsigned short* __restrict__ k,
    const unsigned short* __restrict__ vt,
    unsigned short* __restrict__ o)
{
  __shared__ alignas(16) unsigned short Qs[128][72];
  __shared__ alignas(16) unsigned short Ks[64][72];
  __shared__ alignas(16) unsigned short Vs[64][72];
  const int tid  = threadIdx.x;
  const int wave = tid >> 6;
  const int lane = tid & 63;
  const int quad = lane >> 4;
  const int l16  = lane & 15;
  const int bh = blockIdx.x;
  const int q0 = blockIdx.y * 128;
  const unsigned short* qb = q  + ((size_t)bh << 16);
  const unsigned short* kb = k  + ((size_t)bh << 16);
  const unsigned short* vb = vt + ((size_t)bh << 16);

  #pragma unroll
  for (int i = 0; i < 4; i++) {
    int flat = tid + i * 256;
    int r = flat >> 3, ck = (flat & 7) << 3;
    *(f32x4*)&Qs[r][ck] = *(const f32x4*)&qb[((size_t)(q0 + r) << 6) + ck];
  }
  __syncthreads();
  short8 aq[2][2];
  #pragma unroll
  for (int rg = 0; rg < 2; rg++)
    #pragma unroll
    for (int ks = 0; ks < 2; ks++)
      aq[rg][ks] = *(const short8*)&Qs[wave * 32 + rg * 16 + l16][ks * 32 + quad * 8];
  __syncthreads();  // Q consumed; Qs becomes wave-private P scratch
  unsigned short (*Ps)[72] = (unsigned short (*)[72])(&Qs[wave * 32][0]);

  f32x4 Oacc[2][4] = {};
  float lsum[2][4] = {};

  int sr[2], sc[2];
  #pragma unroll
  for (int i = 0; i < 2; i++) { int f = tid + i * 256; sr[i] = f >> 3; sc[i] = (f & 7) << 3; }

  f32x4 kreg[2], vreg[2];
  #pragma unroll
  for (int i = 0; i < 2; i++) {
    kreg[i] = *(const f32x4*)&kb[((size_t)sr[i] << 6) + sc[i]];
    vreg[i] = *(const f32x4*)&vb[((size_t)sr[i] << 10) + sc[i]];
  }

  for (int kt = 0; kt < 16; kt++) {
    __syncthreads();
    #pragma unroll
    for (int i = 0; i < 2; i++) {
      *(f32x4*)&Ks[sr[i]][sc[i]] = kreg[i];
      *(f32x4*)&Vs[sr[i]][sc[i]] = vreg[i];
    }
    __syncthreads();
    if (kt < 15) {
      #pragma unroll
      for (int i = 0; i < 2; i++) {
        kreg[i] = *(const f32x4*)&kb[((size_t)((kt + 1) * 64 + sr[i]) << 6) + sc[i]];
        vreg[i] = *(const f32x4*)&vb[((size_t)sr[i] << 10) + (kt + 1) * 64 + sc[i]];
      }
    }

    f32x4 s[2][4] = {};
    #pragma unroll
    for (int ks = 0; ks < 2; ks++) {
      const int kk = ks * 32 + quad * 8;
      short8 b0 = *(const short8*)&Ks[l16][kk];
      short8 b1 = *(const short8*)&Ks[16 + l16][kk];
      short8 b2 = *(const short8*)&Ks[32 + l16][kk];
      short8 b3 = *(const short8*)&Ks[48 + l16][kk];
      s[0][0] = MFMA16(aq[0][ks], b0, s[0][0]);
      s[0][1] = MFMA16(aq[0][ks], b1, s[0][1]);
      s[0][2] = MFMA16(aq[0][ks], b2, s[0][2]);
      s[0][3] = MFMA16(aq[0][ks], b3, s[0][3]);
      s[1][0] = MFMA16(aq[1][ks], b0, s[1][0]);
      s[1][1] = MFMA16(aq[1][ks], b1, s[1][1]);
      s[1][2] = MFMA16(aq[1][ks], b2, s[1][2]);
      s[1][3] = MFMA16(aq[1][ks], b3, s[1][3]);
    }

    #pragma unroll
    for (int rg = 0; rg < 2; rg++) {
      #pragma unroll
      for (int r = 0; r < 4; r++) {
        float p0 = exp2f(s[rg][0][r]);
        float p1 = exp2f(s[rg][1][r]);
        float p2 = exp2f(s[rg][2][r]);
        float p3 = exp2f(s[rg][3][r]);
        lsum[rg][r] += (p0 + p1) + (p2 + p3);
        u32x2 pk;
        pk.x = pack2bf(p0, p1);
        pk.y = pack2bf(p2, p3);
        *(u32x2*)&Ps[rg * 16 + quad * 4 + r][4 * l16] = pk;
      }
    }

    #pragma unroll
    for (int ks = 0; ks < 2; ks++) {
      const int kk = ks * 32 + quad * 8;
      short8 a0 = *(const short8*)&Ps[l16][kk];
      short8 a1 = *(const short8*)&Ps[16 + l16][kk];
      short8 v0 = *(const short8*)&Vs[l16][kk];
      short8 v1 = *(const short8*)&Vs[16 + l16][kk];
      short8 v2 = *(const short8*)&Vs[32 + l16][kk];
      short8 v3 = *(const short8*)&Vs[48 + l16][kk];
      Oacc[0][0] = MFMA16(a0, v0, Oacc[0][0]);
      Oacc[0][1] = MFMA16(a0, v1, Oacc[0][1]);
      Oacc[0][2] = MFMA16(a0, v2, Oacc[0][2]);
      Oacc[0][3] = MFMA16(a0, v3, Oacc[0][3]);
      Oacc[1][0] = MFMA16(a1, v0, Oacc[1][0]);
      Oacc[1][1] = MFMA16(a1, v1, Oacc[1][1]);
      Oacc[1][2] = MFMA16(a1, v2, Oacc[1][2]);
      Oacc[1][3] = MFMA16(a1, v3, Oacc[1][3]);
    }
  }

  const int b = bh / 12, h = bh - (bh / 12) * 12;
  #pragma unroll
  for (int rg = 0; rg < 2; rg++) {
    #pragma unroll
    for (int r = 0; r < 4; r++) {
      float t = lsum[rg][r];
      t += __shfl_xor(t, 1, 64);
      t += __shfl_xor(t, 2, 64);
      t += __shfl_xor(t, 4, 64);
      t += __shfl_xor(t, 8, 64);
      float inv = 1.0f / t;
      int np = q0 + wave * 32 + rg * 16 + quad * 4 + r;
      size_t base = ((size_t)(b * 1024 + np)) * 768 + h * 64;
      #pragma unroll
      for (int j = 0; j < 4; j++)
        o[base + j * 16 + l16] = f2bf(Oacc[rg][j][r] * inv);
    }
  }
}

// ---------------------------------------------------------------------------
extern "C" void kernel_launch(void* const* d_in, const int* in_sizes, int n_in,
                              void* d_out, int out_size, void* d_ws, size_t ws_size,
                              hipStream_t stream) {
  const float* x      = (const float*)d_in[0];
  const float* w_qkv  = (const float*)d_in[1];
  const float* b_qkv  = (const float*)d_in[2];
  const float* w_proj = (const float*)d_in[3];
  const float* b_proj = (const float*)d_in[4];
  const float* q_a    = (const float*)d_in[5];
  const float* q_b    = (const float*)d_in[6];
  const float* k_a    = (const float*)d_in[7];
  const float* k_b    = (const float*)d_in[8];
  const float* v_a    = (const float*)d_in[9];
  const float* v_b    = (const float*)d_in[10];
  const float* o_a    = (const float*)d_in[11];
  const float* o_b    = (const float*)d_in[12];

  char* ws = (char*)d_ws;
  unsigned short* wqkv_eff  = (unsigned short*)(ws + 0);          // 3,538,944
  unsigned short* wproj_eff = (unsigned short*)(ws + 3538944);    // 1,179,648
  unsigned short* xb        = (unsigned short*)(ws + 4718592);    // 12,582,912 (reused as od)
  unsigned short* qd        = (unsigned short*)(ws + 17301504);   // 12,582,912
  unsigned short* kd        = (unsigned short*)(ws + 29884416);   // 12,582,912
  unsigned short* vtd       = (unsigned short*)(ws + 42467328);   // 12,582,912 (end 55,050,240)
  unsigned short* od        = xb;  // xb dead after QKV GEMM

  prep<<<dim3(6144 + 9216), dim3(256), 0, stream>>>(
      x, w_qkv, w_proj, q_a, q_b, k_a, k_b, v_a, v_b, o_a, o_b,
      xb, wqkv_eff, wproj_eff);

  gemm_bt<<<dim3(64, 18), dim3(256), 0, stream>>>(
      xb, wqkv_eff, b_qkv, qd, kd, vtd, nullptr, 768, 2304, 0);

  attn<<<dim3(96, 8), dim3(256), 0, stream>>>(qd, kd, vtd, od);

  gemm_bt<<<dim3(64, 6), dim3(256), 0, stream>>>(
      od, wproj_eff, b_proj, nullptr, nullptr, nullptr, (float*)d_out, 768, 768, 1);
}

// Round 9
// 226.291 us; speedup vs baseline: 1.1572x; 1.1572x over previous
//
#include <hip/hip_runtime.h>

typedef __attribute__((ext_vector_type(8))) short short8;
typedef __attribute__((ext_vector_type(4))) float f32x4;
typedef __attribute__((ext_vector_type(4))) unsigned short u16x4;
typedef __attribute__((ext_vector_type(2))) unsigned int u32x2;

#define MFMA16(a,b,c) __builtin_amdgcn_mfma_f32_16x16x32_bf16((a),(b),(c),0,0,0)

// 0.125 (attn scale) * log2(e), folded into Q at the QKV epilogue.
#define QSCALE 0.1803368801f

__device__ __forceinline__ unsigned short f2bf(float f) {
  unsigned int x = __float_as_uint(f);
  x += 0x7fffu + ((x >> 16) & 1u);
  return (unsigned short)(x >> 16);
}
__device__ __forceinline__ unsigned int pack2bf(float a, float b) {
  unsigned int ua = __float_as_uint(a) + 0x8000u;
  unsigned int ub = __float_as_uint(b) + 0x8000u;
  return __builtin_amdgcn_perm(ub, ua, 0x07060302);
}
// async 16B global -> LDS (dest = wave-uniform base + lane*16)
__device__ __forceinline__ void gload16(const unsigned short* g, unsigned short* l) {
  __builtin_amdgcn_global_load_lds(
      (const __attribute__((address_space(1))) unsigned int*)g,
      (__attribute__((address_space(3))) unsigned int*)l, 16, 0, 0);
}

// ---------------------------------------------------------------------------
// Kernel 1: prep = convert_x (blocks < 6144) + build_weights (rest).
// ---------------------------------------------------------------------------
__global__ __launch_bounds__(256) void prep(
    const float* __restrict__ x,
    const float* __restrict__ w_qkv,
    const float* __restrict__ w_proj,
    const float* __restrict__ q_a, const float* __restrict__ q_b,
    const float* __restrict__ k_a, const float* __restrict__ k_b,
    const float* __restrict__ v_a, const float* __restrict__ v_b,
    const float* __restrict__ o_a, const float* __restrict__ o_b,
    unsigned short* __restrict__ xb,
    unsigned short* __restrict__ wqkv_eff,
    unsigned short* __restrict__ wproj_eff)
{
  int bid = blockIdx.x;
  if (bid < 6144) {
    int i4 = (bid * 256 + threadIdx.x) * 4;
    f32x4 v = *(const f32x4*)&x[i4];
    u16x4 o;
    o.x = f2bf(v.x); o.y = f2bf(v.y); o.z = f2bf(v.z); o.w = f2bf(v.w);
    *(u16x4*)&xb[i4] = o;
    return;
  }
  const int QKV = 2304 * 768;
  int idx = (bid - 6144) * 256 + threadIdx.x;
  if (idx < QKV) {
    int n = idx / 768, c = idx - n * 768;
    int sec = n / 768;
    int nr = n - sec * 768;
    const float* a; const float* b;
    if (sec == 0)      { a = q_a; b = q_b; }
    else if (sec == 1) { a = k_a; b = k_b; }
    else               { a = v_a; b = v_b; }
    float acc = w_qkv[idx];
    #pragma unroll
    for (int r = 0; r < 8; r++)
      acc += b[nr * 8 + r] * a[r * 768 + c];
    wqkv_eff[idx] = f2bf(acc);
  } else {
    int i2 = idx - QKV;
    int n = i2 / 768, c = i2 - n * 768;
    float acc = w_proj[i2];
    #pragma unroll
    for (int r = 0; r < 8; r++)
      acc += o_b[n * 8 + r] * o_a[r * 768 + c];
    wproj_eff[i2] = f2bf(acc);
  }
}

// ---------------------------------------------------------------------------
// Kernel 2/4: R4's gemm_bt VERBATIM (measured best: 60.5 us QKV).
// C[M,Ncols] = A[M,K] @ W[Ncols,K]^T + bias. BM=128, BN=64, BK=64; 4 waves x
// 32 rows; padded LDS; VGPR-roundtrip staging with register prefetch.
// Five structures tested (R4-R8): this one wins at K=768 (12 iters).
// ---------------------------------------------------------------------------
__global__ __launch_bounds__(256) void gemm_bt(
    const unsigned short* __restrict__ A,
    const unsigned short* __restrict__ W,
    const float* __restrict__ bias,
    unsigned short* __restrict__ out0,
    unsigned short* __restrict__ out1,
    unsigned short* __restrict__ out2,
    float* __restrict__ outf,
    int K, int Ncols, int mode)
{
  __shared__ alignas(16) unsigned short As[128][72];
  __shared__ alignas(16) unsigned short Ws[64][72];
  const int tid  = threadIdx.x;
  const int wave = tid >> 6;
  const int lane = tid & 63;
  const int quad = lane >> 4;
  const int l16  = lane & 15;
  const int m0 = blockIdx.x * 128;
  const int n0 = blockIdx.y * 64;

  int ar[4], ac[4], wr[2], wc[2];
  #pragma unroll
  for (int i = 0; i < 4; i++) { int f = tid + i * 256; ar[i] = f >> 3; ac[i] = (f & 7) << 3; }
  #pragma unroll
  for (int i = 0; i < 2; i++) { int f = tid + i * 256; wr[i] = f >> 3; wc[i] = (f & 7) << 3; }

  f32x4 areg[4], wreg[2];
  #pragma unroll
  for (int i = 0; i < 4; i++)
    areg[i] = *(const f32x4*)&A[(size_t)(m0 + ar[i]) * K + ac[i]];
  #pragma unroll
  for (int i = 0; i < 2; i++)
    wreg[i] = *(const f32x4*)&W[(size_t)(n0 + wr[i]) * K + wc[i]];

  f32x4 acc[2][4] = {};

  for (int k0 = 0; k0 < K; k0 += 64) {
    __syncthreads();
    #pragma unroll
    for (int i = 0; i < 4; i++) *(f32x4*)&As[ar[i]][ac[i]] = areg[i];
    #pragma unroll
    for (int i = 0; i < 2; i++) *(f32x4*)&Ws[wr[i]][wc[i]] = wreg[i];
    __syncthreads();
    if (k0 + 64 < K) {
      #pragma unroll
      for (int i = 0; i < 4; i++)
        areg[i] = *(const f32x4*)&A[(size_t)(m0 + ar[i]) * K + k0 + 64 + ac[i]];
      #pragma unroll
      for (int i = 0; i < 2; i++)
        wreg[i] = *(const f32x4*)&W[(size_t)(n0 + wr[i]) * K + k0 + 64 + wc[i]];
    }
    #pragma unroll
    for (int ks = 0; ks < 2; ks++) {
      const int kk = ks * 32 + quad * 8;
      short8 a0 = *(const short8*)&As[wave * 32 + l16][kk];
      short8 a1 = *(const short8*)&As[wave * 32 + 16 + l16][kk];
      short8 b0 = *(const short8*)&Ws[l16][kk];
      short8 b1 = *(const short8*)&Ws[16 + l16][kk];
      short8 b2 = *(const short8*)&Ws[32 + l16][kk];
      short8 b3 = *(const short8*)&Ws[48 + l16][kk];
      acc[0][0] = MFMA16(a0, b0, acc[0][0]);
      acc[0][1] = MFMA16(a0, b1, acc[0][1]);
      acc[0][2] = MFMA16(a0, b2, acc[0][2]);
      acc[0][3] = MFMA16(a0, b3, acc[0][3]);
      acc[1][0] = MFMA16(a1, b0, acc[1][0]);
      acc[1][1] = MFMA16(a1, b1, acc[1][1]);
      acc[1][2] = MFMA16(a1, b2, acc[1][2]);
      acc[1][3] = MFMA16(a1, b3, acc[1][3]);
    }
  }

  float bv[4];
  #pragma unroll
  for (int j = 0; j < 4; j++) bv[j] = bias[n0 + j * 16 + l16];

  if (mode == 0) {
    const int sec = n0 / 768;                 // uniform per block
    const int h   = (n0 % 768) >> 6;
    unsigned short* dst = (sec == 0) ? out0 : ((sec == 1) ? out1 : out2);
    const float scl = (sec == 0) ? QSCALE : 1.0f;
    #pragma unroll
    for (int rg = 0; rg < 2; rg++) {
      #pragma unroll
      for (int r = 0; r < 4; r++) {
        int m  = m0 + wave * 32 + rg * 16 + quad * 4 + r;
        int b  = m >> 10, np = m & 1023;
        int bh = b * 12 + h;
        int npp = (np & ~63) | ((np & 15) * 4 + ((np >> 4) & 3)); // key perm
        #pragma unroll
        for (int j = 0; j < 4; j++) {
          int d = j * 16 + l16;
          float v = (acc[rg][j][r] + bv[j]) * scl;
          if (sec < 2) dst[((size_t)bh << 16) + ((size_t)np << 6) + d] = f2bf(v);
          else         dst[((size_t)bh << 16) + ((size_t)d << 10) + npp] = f2bf(v);
        }
      }
    }
  } else {
    #pragma unroll
    for (int rg = 0; rg < 2; rg++) {
      #pragma unroll
      for (int r = 0; r < 4; r++) {
        int m = m0 + wave * 32 + rg * 16 + quad * 4 + r;
        #pragma unroll
        for (int j = 0; j < 4; j++)
          outf[(size_t)m * Ncols + n0 + j * 16 + l16] = acc[rg][j][r] + bv[j];
      }
    }
  }
}

// ---------------------------------------------------------------------------
// Kernel 3: flash attention, 1-barrier K-loop. K/V double-buffered in LDS via
// async global_load_lds(16B), unpadded 64x64 tiles with XOR swizzle (chunk ^
// (row&7), applied on the global gather side; 0 conflicts - R5-verified
// scheme). Per iter: barrier -> stage(kt+1 -> buf 1-p) -> S-MFMA / softmax /
// P-write (wave-private padded scratch, no barrier) / PV-MFMA from buf p.
// Pre-barrier vmcnt(0) drains staging issued a full compute phase earlier.
// Grid (96 bh, 8 q-tiles) -> same-head blocks land on one XCD.
// ---------------------------------------------------------------------------
__global__ __launch_bounds__(256) void attn(
    const unsigned short* __restrict__ q,
    const unsigned short* __restrict__ k,
    const unsigned short* __restrict__ vt,
    unsigned short* __restrict__ o)
{
  __shared__ alignas(16) unsigned short Qs[128][72];      // Q stage -> P scratch
  __shared__ alignas(16) unsigned short Ks2[2][64 * 64];  // 2 x 8 KB
  __shared__ alignas(16) unsigned short Vs2[2][64 * 64];  // 2 x 8 KB
  const int tid  = threadIdx.x;
  const int wave = tid >> 6;
  const int lane = tid & 63;
  const int quad = lane >> 4;
  const int l16  = lane & 15;
  const int bh = blockIdx.x;
  const int q0 = blockIdx.y * 128;
  const unsigned short* qb = q  + ((size_t)bh << 16);
  const unsigned short* kb = k  + ((size_t)bh << 16);
  const unsigned short* vb = vt + ((size_t)bh << 16);

  // K/V staging: wave stages rows [wave*16, +16) of each tile; 2 gload16 per
  // tile; lane -> row +(lane>>3), global chunk (lane&7)^(lane>>3),
  // LDS slot (lane&7) (= HW base+lane*16 pattern).
  const int lrow   = lane >> 3;
  const int lchunk = (lane & 7) ^ lrow;
  const unsigned short* gK[2];
  const unsigned short* gV[2];
  int lsKV[2];
  #pragma unroll
  for (int t = 0; t < 2; t++) {
    int rr = wave * 16 + t * 8 + lrow;
    gK[t]   = kb + (size_t)rr * 64 + lchunk * 8;     // k[bh][key][64]
    gV[t]   = vb + (size_t)rr * 1024 + lchunk * 8;   // vt[bh][d][1024]
    lsKV[t] = rr * 64 + (lane & 7) * 8;
  }
  const int swz = l16 & 7;

  // stage kt=0 into buf 0 first (lands during the Q roundtrip)
  #pragma unroll
  for (int t = 0; t < 2; t++) {
    gload16(gK[t], &Ks2[0][lsKV[t]]);
    gload16(gV[t], &Vs2[0][lsKV[t]]);
  }

  // Q -> LDS -> A-frags (once)
  #pragma unroll
  for (int i = 0; i < 4; i++) {
    int flat = tid + i * 256;
    int r = flat >> 3, ck = (flat & 7) << 3;
    *(f32x4*)&Qs[r][ck] = *(const f32x4*)&qb[((size_t)(q0 + r) << 6) + ck];
  }
  __syncthreads();
  short8 aq[2][2];
  #pragma unroll
  for (int rg = 0; rg < 2; rg++)
    #pragma unroll
    for (int ks = 0; ks < 2; ks++)
      aq[rg][ks] = *(const short8*)&Qs[wave * 32 + rg * 16 + l16][ks * 32 + quad * 8];
  unsigned short (*Ps)[72] = (unsigned short (*)[72])(&Qs[wave * 32][0]);

  f32x4 Oacc[2][4] = {};
  float lsum[2][4] = {};

  for (int kt = 0; kt < 16; kt++) {
    const int p = kt & 1;
    __syncthreads();   // drains own staging (vmcnt 0) + all waves' Q/P reads
    if (kt < 15) {
      #pragma unroll
      for (int t = 0; t < 2; t++) {
        gload16(gK[t] + (kt + 1) * 4096, &Ks2[1 - p][lsKV[t]]);
        gload16(gV[t] + (kt + 1) * 64,   &Vs2[1 - p][lsKV[t]]);
      }
    }

    // S = Q K^T from Ks2[p] (swizzled read: chunk cs ^ (row&7))
    f32x4 s[2][4] = {};
    #pragma unroll
    for (int ks = 0; ks < 2; ks++) {
      const int cs = ks * 4 + quad;
      short8 b0 = *(const short8*)&Ks2[p][(l16)      * 64 + ((cs ^ swz) << 3)];
      short8 b1 = *(const short8*)&Ks2[p][(16 + l16) * 64 + ((cs ^ swz) << 3)];
      short8 b2 = *(const short8*)&Ks2[p][(32 + l16) * 64 + ((cs ^ swz) << 3)];
      short8 b3 = *(const short8*)&Ks2[p][(48 + l16) * 64 + ((cs ^ swz) << 3)];
      s[0][0] = MFMA16(aq[0][ks], b0, s[0][0]);
      s[0][1] = MFMA16(aq[0][ks], b1, s[0][1]);
      s[0][2] = MFMA16(aq[0][ks], b2, s[0][2]);
      s[0][3] = MFMA16(aq[0][ks], b3, s[0][3]);
      s[1][0] = MFMA16(aq[1][ks], b0, s[1][0]);
      s[1][1] = MFMA16(aq[1][ks], b1, s[1][1]);
      s[1][2] = MFMA16(aq[1][ks], b2, s[1][2]);
      s[1][3] = MFMA16(aq[1][ks], b3, s[1][3]);
    }

    // P = exp2(S) (Q pre-scaled); packed 8B write per row into wave-private Ps.
    // P col kappa = 4*l16 + j matches vt's key permutation.
    #pragma unroll
    for (int rg = 0; rg < 2; rg++) {
      #pragma unroll
      for (int r = 0; r < 4; r++) {
        float p0 = exp2f(s[rg][0][r]);
        float p1 = exp2f(s[rg][1][r]);
        float p2 = exp2f(s[rg][2][r]);
        float p3 = exp2f(s[rg][3][r]);
        lsum[rg][r] += (p0 + p1) + (p2 + p3);
        u32x2 pk;
        pk.x = pack2bf(p0, p1);
        pk.y = pack2bf(p2, p3);
        *(u32x2*)&Ps[rg * 16 + quad * 4 + r][4 * l16] = pk;
      }
    }

    // O += P V from Vs2[p]
    #pragma unroll
    for (int ks = 0; ks < 2; ks++) {
      const int kk = ks * 32 + quad * 8;
      const int cs = ks * 4 + quad;
      short8 a0 = *(const short8*)&Ps[l16][kk];
      short8 a1 = *(const short8*)&Ps[16 + l16][kk];
      short8 v0 = *(const short8*)&Vs2[p][(l16)      * 64 + ((cs ^ swz) << 3)];
      short8 v1 = *(const short8*)&Vs2[p][(16 + l16) * 64 + ((cs ^ swz) << 3)];
      short8 v2 = *(const short8*)&Vs2[p][(32 + l16) * 64 + ((cs ^ swz) << 3)];
      short8 v3 = *(const short8*)&Vs2[p][(48 + l16) * 64 + ((cs ^ swz) << 3)];
      Oacc[0][0] = MFMA16(a0, v0, Oacc[0][0]);
      Oacc[0][1] = MFMA16(a0, v1, Oacc[0][1]);
      Oacc[0][2] = MFMA16(a0, v2, Oacc[0][2]);
      Oacc[0][3] = MFMA16(a0, v3, Oacc[0][3]);
      Oacc[1][0] = MFMA16(a1, v0, Oacc[1][0]);
      Oacc[1][1] = MFMA16(a1, v1, Oacc[1][1]);
      Oacc[1][2] = MFMA16(a1, v2, Oacc[1][2]);
      Oacc[1][3] = MFMA16(a1, v3, Oacc[1][3]);
    }
  }

  const int b = bh / 12, h = bh - (bh / 12) * 12;
  #pragma unroll
  for (int rg = 0; rg < 2; rg++) {
    #pragma unroll
    for (int r = 0; r < 4; r++) {
      float t = lsum[rg][r];
      t += __shfl_xor(t, 1, 64);
      t += __shfl_xor(t, 2, 64);
      t += __shfl_xor(t, 4, 64);
      t += __shfl_xor(t, 8, 64);
      float inv = 1.0f / t;
      int np = q0 + wave * 32 + rg * 16 + quad * 4 + r;
      size_t base = ((size_t)(b * 1024 + np)) * 768 + h * 64;
      #pragma unroll
      for (int j = 0; j < 4; j++)
        o[base + j * 16 + l16] = f2bf(Oacc[rg][j][r] * inv);
    }
  }
}

// ---------------------------------------------------------------------------
extern "C" void kernel_launch(void* const* d_in, const int* in_sizes, int n_in,
                              void* d_out, int out_size, void* d_ws, size_t ws_size,
                              hipStream_t stream) {
  const float* x      = (const float*)d_in[0];
  const float* w_qkv  = (const float*)d_in[1];
  const float* b_qkv  = (const float*)d_in[2];
  const float* w_proj = (const float*)d_in[3];
  const float* b_proj = (const float*)d_in[4];
  const float* q_a    = (const float*)d_in[5];
  const float* q_b    = (const float*)d_in[6];
  const float* k_a    = (const float*)d_in[7];
  const float* k_b    = (const float*)d_in[8];
  const float* v_a    = (const float*)d_in[9];
  const float* v_b    = (const float*)d_in[10];
  const float* o_a    = (const float*)d_in[11];
  const float* o_b    = (const float*)d_in[12];

  char* ws = (char*)d_ws;
  unsigned short* wqkv_eff  = (unsigned short*)(ws + 0);          // 3,538,944
  unsigned short* wproj_eff = (unsigned short*)(ws + 3538944);    // 1,179,648
  unsigned short* xb        = (unsigned short*)(ws + 4718592);    // 12,582,912 (reused as od)
  unsigned short* qd        = (unsigned short*)(ws + 17301504);   // 12,582,912
  unsigned short* kd        = (unsigned short*)(ws + 29884416);   // 12,582,912
  unsigned short* vtd       = (unsigned short*)(ws + 42467328);   // 12,582,912 (end 55,050,240)
  unsigned short* od        = xb;  // xb dead after QKV GEMM

  prep<<<dim3(6144 + 9216), dim3(256), 0, stream>>>(
      x, w_qkv, w_proj, q_a, q_b, k_a, k_b, v_a, v_b, o_a, o_b,
      xb, wqkv_eff, wproj_eff);

  gemm_bt<<<dim3(64, 36), dim3(256), 0, stream>>>(
      xb, wqkv_eff, b_qkv, qd, kd, vtd, nullptr, 768, 2304, 0);

  attn<<<dim3(96, 8), dim3(256), 0, stream>>>(qd, kd, vtd, od);

  gemm_bt<<<dim3(64, 12), dim3(256), 0, stream>>>(
      od, wproj_eff, b_proj, nullptr, nullptr, nullptr, (float*)d_out, 768, 768, 1);
}

// Round 10
// 223.484 us; speedup vs baseline: 1.1717x; 1.0126x over previous
//
#include <hip/hip_runtime.h>

typedef __attribute__((ext_vector_type(8))) short short8;
typedef __attribute__((ext_vector_type(4))) float f32x4;
typedef __attribute__((ext_vector_type(4))) unsigned short u16x4;
typedef __attribute__((ext_vector_type(2))) unsigned int u32x2;

#define MFMA16(a,b,c) __builtin_amdgcn_mfma_f32_16x16x32_bf16((a),(b),(c),0,0,0)

// 0.125 (attn scale) * log2(e), folded into Q at the QKV epilogue.
#define QSCALE 0.1803368801f

__device__ __forceinline__ unsigned short f2bf(float f) {
  unsigned int x = __float_as_uint(f);
  x += 0x7fffu + ((x >> 16) & 1u);
  return (unsigned short)(x >> 16);
}
__device__ __forceinline__ unsigned int pack2bf(float a, float b) {
  unsigned int ua = __float_as_uint(a) + 0x8000u;
  unsigned int ub = __float_as_uint(b) + 0x8000u;
  return __builtin_amdgcn_perm(ub, ua, 0x07060302);
}
// async 16B global -> LDS (dest = wave-uniform base + lane*16)
__device__ __forceinline__ void gload16(const unsigned short* g, unsigned short* l) {
  __builtin_amdgcn_global_load_lds(
      (const __attribute__((address_space(1))) unsigned int*)g,
      (__attribute__((address_space(3))) unsigned int*)l, 16, 0, 0);
}

// Fragment-major A layout: elem(m,k) -> xf[((k>>5)*512 + (m>>4))*512 +
// (((k>>3)&3)*16 + (m&15))*8 + (k&7)].  A wave's 16x32 MFMA A-frag (row-tile
// M16, k-block kb) is then 1 KB contiguous: base + lane*16B, one coalesced
// global_load_dwordx4 per lane. 512 = 8192/16 M16-tiles; kb = k/32.

// ---------------------------------------------------------------------------
// Kernel 1: prep = convert x -> frag-major bf16 (blocks < 6144) +
//                  build LoRA-folded weights (rest).
// ---------------------------------------------------------------------------
__global__ __launch_bounds__(256) void prep(
    const float* __restrict__ x,
    const float* __restrict__ w_qkv,
    const float* __restrict__ w_proj,
    const float* __restrict__ q_a, const float* __restrict__ q_b,
    const float* __restrict__ k_a, const float* __restrict__ k_b,
    const float* __restrict__ v_a, const float* __restrict__ v_b,
    const float* __restrict__ o_a, const float* __restrict__ o_b,
    unsigned short* __restrict__ xf,
    unsigned short* __restrict__ wqkv_eff,
    unsigned short* __restrict__ wproj_eff)
{
  int bid = blockIdx.x;
  if (bid < 6144) {
    int i4 = (bid * 256 + threadIdx.x) * 4;
    int m  = i4 / 768;
    int k4 = i4 - m * 768;             // 4 consecutive k, same 8-chunk half
    f32x4 v = *(const f32x4*)&x[i4];
    u16x4 o;
    o.x = f2bf(v.x); o.y = f2bf(v.y); o.z = f2bf(v.z); o.w = f2bf(v.w);
    int kb = k4 >> 5, qd = (k4 >> 3) & 3, j0 = k4 & 7;
    size_t idx = ((size_t)(kb * 512 + (m >> 4)) << 9) +
                 (((qd << 4) + (m & 15)) << 3) + j0;
    *(u16x4*)&xf[idx] = o;
    return;
  }
  const int QKV = 2304 * 768;
  int idx = (bid - 6144) * 256 + threadIdx.x;
  if (idx < QKV) {
    int n = idx / 768, c = idx - n * 768;
    int sec = n / 768;
    int nr = n - sec * 768;
    const float* a; const float* b;
    if (sec == 0)      { a = q_a; b = q_b; }
    else if (sec == 1) { a = k_a; b = k_b; }
    else               { a = v_a; b = v_b; }
    float acc = w_qkv[idx];
    #pragma unroll
    for (int r = 0; r < 8; r++)
      acc += b[nr * 8 + r] * a[r * 768 + c];
    wqkv_eff[idx] = f2bf(acc);
  } else {
    int i2 = idx - QKV;
    int n = i2 / 768, c = i2 - n * 768;
    float acc = w_proj[i2];
    #pragma unroll
    for (int r = 0; r < 8; r++)
      acc += o_b[n * 8 + r] * o_a[r * 768 + c];
    wproj_eff[i2] = f2bf(acc);
  }
}

// ---------------------------------------------------------------------------
// Kernel 2/4: C[M,Ncols] = A@W^T + bias. A in FRAG-MAJOR layout, loaded
// direct global->register (coalesced 1KB/wave), prefetched one iter ahead
// (R4's proven prefetch pattern). W via R4 padded-LDS VGPR-roundtrip with
// register prefetch. LDS traffic 72->40 KB/block-iter (the measured R4
// bottleneck: LDS pipe saturated at 2.5 blocks/CU); LDS footprint 27.6->9.2KB.
// BM=128, BN=64, BK=64; 4 waves x 32 rows.
// mode 0 (QKV): Q*QSCALE -> q[BH][N][64]; K -> k[BH][N][64];
//               V -> vt[BH][64][1024], key-permuted cols (4*(np&15)+((np>>4)&3)).
// mode 1: fp32 row-major store (final output).
// ---------------------------------------------------------------------------
__global__ __launch_bounds__(256) void gemm_bt(
    const unsigned short* __restrict__ Af,
    const unsigned short* __restrict__ W,
    const float* __restrict__ bias,
    unsigned short* __restrict__ out0,
    unsigned short* __restrict__ out1,
    unsigned short* __restrict__ out2,
    float* __restrict__ outf,
    int K, int Ncols, int mode)
{
  __shared__ alignas(16) unsigned short Ws[64][72];
  const int tid  = threadIdx.x;
  const int wave = tid >> 6;
  const int lane = tid & 63;
  const int quad = lane >> 4;
  const int l16  = lane & 15;
  const int m0 = blockIdx.x * 128;
  const int n0 = blockIdx.y * 64;
  const int M16b = (m0 >> 4) + wave * 2;       // wave's row-tiles: M16b, M16b+1

  int wr[2], wc[2];
  #pragma unroll
  for (int i = 0; i < 2; i++) { int f = tid + i * 256; wr[i] = f >> 3; wc[i] = (f & 7) << 3; }

  f32x4 wreg[2];
  #pragma unroll
  for (int i = 0; i < 2; i++)
    wreg[i] = *(const f32x4*)&W[(size_t)(n0 + wr[i]) * K + wc[i]];

  short8 aCur[2][2], aNxt[2][2] = {};          // [row-tile t][ks]
  #pragma unroll
  for (int t = 0; t < 2; t++)
    #pragma unroll
    for (int ks = 0; ks < 2; ks++)
      aCur[t][ks] = *(const short8*)&Af[((size_t)(ks * 512 + M16b + t) << 9) + (lane << 3)];

  f32x4 acc[2][4] = {};

  for (int k0 = 0; k0 < K; k0 += 64) {
    __syncthreads();
    #pragma unroll
    for (int i = 0; i < 2; i++) *(f32x4*)&Ws[wr[i]][wc[i]] = wreg[i];
    __syncthreads();
    if (k0 + 64 < K) {
      #pragma unroll
      for (int i = 0; i < 2; i++)
        wreg[i] = *(const f32x4*)&W[(size_t)(n0 + wr[i]) * K + k0 + 64 + wc[i]];
      const int kbn = (k0 + 64) >> 5;
      #pragma unroll
      for (int t = 0; t < 2; t++)
        #pragma unroll
        for (int ks = 0; ks < 2; ks++)
          aNxt[t][ks] = *(const short8*)&Af[((size_t)((kbn + ks) * 512 + M16b + t) << 9) + (lane << 3)];
    }
    #pragma unroll
    for (int ks = 0; ks < 2; ks++) {
      const int kk = ks * 32 + quad * 8;
      short8 b0 = *(const short8*)&Ws[l16][kk];
      short8 b1 = *(const short8*)&Ws[16 + l16][kk];
      short8 b2 = *(const short8*)&Ws[32 + l16][kk];
      short8 b3 = *(const short8*)&Ws[48 + l16][kk];
      acc[0][0] = MFMA16(aCur[0][ks], b0, acc[0][0]);
      acc[0][1] = MFMA16(aCur[0][ks], b1, acc[0][1]);
      acc[0][2] = MFMA16(aCur[0][ks], b2, acc[0][2]);
      acc[0][3] = MFMA16(aCur[0][ks], b3, acc[0][3]);
      acc[1][0] = MFMA16(aCur[1][ks], b0, acc[1][0]);
      acc[1][1] = MFMA16(aCur[1][ks], b1, acc[1][1]);
      acc[1][2] = MFMA16(aCur[1][ks], b2, acc[1][2]);
      acc[1][3] = MFMA16(aCur[1][ks], b3, acc[1][3]);
    }
    #pragma unroll
    for (int t = 0; t < 2; t++)
      #pragma unroll
      for (int ks = 0; ks < 2; ks++)
        aCur[t][ks] = aNxt[t][ks];
  }

  float bv[4];
  #pragma unroll
  for (int j = 0; j < 4; j++) bv[j] = bias[n0 + j * 16 + l16];

  if (mode == 0) {
    const int sec = n0 / 768;
    const int h   = (n0 % 768) >> 6;
    unsigned short* dst = (sec == 0) ? out0 : ((sec == 1) ? out1 : out2);
    const float scl = (sec == 0) ? QSCALE : 1.0f;
    #pragma unroll
    for (int rg = 0; rg < 2; rg++) {
      #pragma unroll
      for (int r = 0; r < 4; r++) {
        int m  = m0 + wave * 32 + rg * 16 + quad * 4 + r;
        int b  = m >> 10, np = m & 1023;
        int bh = b * 12 + h;
        int npp = (np & ~63) | ((np & 15) * 4 + ((np >> 4) & 3)); // key perm
        #pragma unroll
        for (int j = 0; j < 4; j++) {
          int d = j * 16 + l16;
          float v = (acc[rg][j][r] + bv[j]) * scl;
          if (sec < 2) dst[((size_t)bh << 16) + ((size_t)np << 6) + d] = f2bf(v);
          else         dst[((size_t)bh << 16) + ((size_t)d << 10) + npp] = f2bf(v);
        }
      }
    }
  } else {
    #pragma unroll
    for (int rg = 0; rg < 2; rg++) {
      #pragma unroll
      for (int r = 0; r < 4; r++) {
        int m = m0 + wave * 32 + rg * 16 + quad * 4 + r;
        #pragma unroll
        for (int j = 0; j < 4; j++)
          outf[(size_t)m * Ncols + n0 + j * 16 + l16] = acc[rg][j][r] + bv[j];
      }
    }
  }
}

// ---------------------------------------------------------------------------
// Kernel 3: flash attention (R9 structure: 1-barrier, K/V dbuf via gload16,
// swizzled). Only change: O is stored in FRAG-MAJOR layout so the proj GEMM
// reads it through the fast A-path.
// ---------------------------------------------------------------------------
__global__ __launch_bounds__(256) void attn(
    const unsigned short* __restrict__ q,
    const unsigned short* __restrict__ k,
    const unsigned short* __restrict__ vt,
    unsigned short* __restrict__ of)
{
  __shared__ alignas(16) unsigned short Qs[128][72];      // Q stage -> P scratch
  __shared__ alignas(16) unsigned short Ks2[2][64 * 64];  // 2 x 8 KB
  __shared__ alignas(16) unsigned short Vs2[2][64 * 64];  // 2 x 8 KB
  const int tid  = threadIdx.x;
  const int wave = tid >> 6;
  const int lane = tid & 63;
  const int quad = lane >> 4;
  const int l16  = lane & 15;
  const int bh = blockIdx.x;
  const int q0 = blockIdx.y * 128;
  const unsigned short* qb = q  + ((size_t)bh << 16);
  const unsigned short* kb = k  + ((size_t)bh << 16);
  const unsigned short* vb = vt + ((size_t)bh << 16);

  const int lrow   = lane >> 3;
  const int lchunk = (lane & 7) ^ lrow;
  const unsigned short* gK[2];
  const unsigned short* gV[2];
  int lsKV[2];
  #pragma unroll
  for (int t = 0; t < 2; t++) {
    int rr = wave * 16 + t * 8 + lrow;
    gK[t]   = kb + (size_t)rr * 64 + lchunk * 8;
    gV[t]   = vb + (size_t)rr * 1024 + lchunk * 8;
    lsKV[t] = rr * 64 + (lane & 7) * 8;
  }
  const int swz = l16 & 7;

  #pragma unroll
  for (int t = 0; t < 2; t++) {
    gload16(gK[t], &Ks2[0][lsKV[t]]);
    gload16(gV[t], &Vs2[0][lsKV[t]]);
  }

  #pragma unroll
  for (int i = 0; i < 4; i++) {
    int flat = tid + i * 256;
    int r = flat >> 3, ck = (flat & 7) << 3;
    *(f32x4*)&Qs[r][ck] = *(const f32x4*)&qb[((size_t)(q0 + r) << 6) + ck];
  }
  __syncthreads();
  short8 aq[2][2];
  #pragma unroll
  for (int rg = 0; rg < 2; rg++)
    #pragma unroll
    for (int ks = 0; ks < 2; ks++)
      aq[rg][ks] = *(const short8*)&Qs[wave * 32 + rg * 16 + l16][ks * 32 + quad * 8];
  unsigned short (*Ps)[72] = (unsigned short (*)[72])(&Qs[wave * 32][0]);

  f32x4 Oacc[2][4] = {};
  float lsum[2][4] = {};

  for (int kt = 0; kt < 16; kt++) {
    const int p = kt & 1;
    __syncthreads();
    if (kt < 15) {
      #pragma unroll
      for (int t = 0; t < 2; t++) {
        gload16(gK[t] + (kt + 1) * 4096, &Ks2[1 - p][lsKV[t]]);
        gload16(gV[t] + (kt + 1) * 64,   &Vs2[1 - p][lsKV[t]]);
      }
    }

    f32x4 s[2][4] = {};
    #pragma unroll
    for (int ks = 0; ks < 2; ks++) {
      const int cs = ks * 4 + quad;
      short8 b0 = *(const short8*)&Ks2[p][(l16)      * 64 + ((cs ^ swz) << 3)];
      short8 b1 = *(const short8*)&Ks2[p][(16 + l16) * 64 + ((cs ^ swz) << 3)];
      short8 b2 = *(const short8*)&Ks2[p][(32 + l16) * 64 + ((cs ^ swz) << 3)];
      short8 b3 = *(const short8*)&Ks2[p][(48 + l16) * 64 + ((cs ^ swz) << 3)];
      s[0][0] = MFMA16(aq[0][ks], b0, s[0][0]);
      s[0][1] = MFMA16(aq[0][ks], b1, s[0][1]);
      s[0][2] = MFMA16(aq[0][ks], b2, s[0][2]);
      s[0][3] = MFMA16(aq[0][ks], b3, s[0][3]);
      s[1][0] = MFMA16(aq[1][ks], b0, s[1][0]);
      s[1][1] = MFMA16(aq[1][ks], b1, s[1][1]);
      s[1][2] = MFMA16(aq[1][ks], b2, s[1][2]);
      s[1][3] = MFMA16(aq[1][ks], b3, s[1][3]);
    }

    #pragma unroll
    for (int rg = 0; rg < 2; rg++) {
      #pragma unroll
      for (int r = 0; r < 4; r++) {
        float p0 = exp2f(s[rg][0][r]);
        float p1 = exp2f(s[rg][1][r]);
        float p2 = exp2f(s[rg][2][r]);
        float p3 = exp2f(s[rg][3][r]);
        lsum[rg][r] += (p0 + p1) + (p2 + p3);
        u32x2 pk;
        pk.x = pack2bf(p0, p1);
        pk.y = pack2bf(p2, p3);
        *(u32x2*)&Ps[rg * 16 + quad * 4 + r][4 * l16] = pk;
      }
    }

    #pragma unroll
    for (int ks = 0; ks < 2; ks++) {
      const int kk = ks * 32 + quad * 8;
      const int cs = ks * 4 + quad;
      short8 a0 = *(const short8*)&Ps[l16][kk];
      short8 a1 = *(const short8*)&Ps[16 + l16][kk];
      short8 v0 = *(const short8*)&Vs2[p][(l16)      * 64 + ((cs ^ swz) << 3)];
      short8 v1 = *(const short8*)&Vs2[p][(16 + l16) * 64 + ((cs ^ swz) << 3)];
      short8 v2 = *(const short8*)&Vs2[p][(32 + l16) * 64 + ((cs ^ swz) << 3)];
      short8 v3 = *(const short8*)&Vs2[p][(48 + l16) * 64 + ((cs ^ swz) << 3)];
      Oacc[0][0] = MFMA16(a0, v0, Oacc[0][0]);
      Oacc[0][1] = MFMA16(a0, v1, Oacc[0][1]);
      Oacc[0][2] = MFMA16(a0, v2, Oacc[0][2]);
      Oacc[0][3] = MFMA16(a0, v3, Oacc[0][3]);
      Oacc[1][0] = MFMA16(a1, v0, Oacc[1][0]);
      Oacc[1][1] = MFMA16(a1, v1, Oacc[1][1]);
      Oacc[1][2] = MFMA16(a1, v2, Oacc[1][2]);
      Oacc[1][3] = MFMA16(a1, v3, Oacc[1][3]);
    }
  }

  // O store in FRAG-MAJOR layout (proj GEMM's A-path):
  // row M = b*1024+np -> M16 = b*64 + (np>>4), l16m = np&15;
  // col = h*64 + j*16 + l16 -> kb = col>>5, qc = (col>>3)&3, jj = l16&7.
  const int b = bh / 12, h = bh - (bh / 12) * 12;
  #pragma unroll
  for (int rg = 0; rg < 2; rg++) {
    #pragma unroll
    for (int r = 0; r < 4; r++) {
      float t = lsum[rg][r];
      t += __shfl_xor(t, 1, 64);
      t += __shfl_xor(t, 2, 64);
      t += __shfl_xor(t, 4, 64);
      t += __shfl_xor(t, 8, 64);
      float inv = 1.0f / t;
      int np  = q0 + wave * 32 + rg * 16 + quad * 4 + r;
      int M16 = b * 64 + (np >> 4);
      int l16m = np & 15;
      #pragma unroll
      for (int j = 0; j < 4; j++) {
        int col = h * 64 + j * 16 + l16;
        int kb2 = col >> 5;
        int qc  = (col >> 3) & 3;
        size_t idx = ((size_t)(kb2 * 512 + M16) << 9) +
                     ((qc * 16 + l16m) << 3) + (l16 & 7);
        of[idx] = f2bf(Oacc[rg][j][r] * inv);
      }
    }
  }
}

// ---------------------------------------------------------------------------
extern "C" void kernel_launch(void* const* d_in, const int* in_sizes, int n_in,
                              void* d_out, int out_size, void* d_ws, size_t ws_size,
                              hipStream_t stream) {
  const float* x      = (const float*)d_in[0];
  const float* w_qkv  = (const float*)d_in[1];
  const float* b_qkv  = (const float*)d_in[2];
  const float* w_proj = (const float*)d_in[3];
  const float* b_proj = (const float*)d_in[4];
  const float* q_a    = (const float*)d_in[5];
  const float* q_b    = (const float*)d_in[6];
  const float* k_a    = (const float*)d_in[7];
  const float* k_b    = (const float*)d_in[8];
  const float* v_a    = (const float*)d_in[9];
  const float* v_b    = (const float*)d_in[10];
  const float* o_a    = (const float*)d_in[11];
  const float* o_b    = (const float*)d_in[12];

  char* ws = (char*)d_ws;
  unsigned short* wqkv_eff  = (unsigned short*)(ws + 0);          // 3,538,944
  unsigned short* wproj_eff = (unsigned short*)(ws + 3538944);    // 1,179,648
  unsigned short* xf        = (unsigned short*)(ws + 4718592);    // 12,582,912 (frag-major; reused as of)
  unsigned short* qd        = (unsigned short*)(ws + 17301504);   // 12,582,912
  unsigned short* kd        = (unsigned short*)(ws + 29884416);   // 12,582,912
  unsigned short* vtd       = (unsigned short*)(ws + 42467328);   // 12,582,912 (end 55,050,240)
  unsigned short* of        = xf;  // xf dead after QKV GEMM

  prep<<<dim3(6144 + 9216), dim3(256), 0, stream>>>(
      x, w_qkv, w_proj, q_a, q_b, k_a, k_b, v_a, v_b, o_a, o_b,
      xf, wqkv_eff, wproj_eff);

  gemm_bt<<<dim3(64, 36), dim3(256), 0, stream>>>(
      xf, wqkv_eff, b_qkv, qd, kd, vtd, nullptr, 768, 2304, 0);

  attn<<<dim3(96, 8), dim3(256), 0, stream>>>(qd, kd, vtd, of);

  gemm_bt<<<dim3(64, 12), dim3(256), 0, stream>>>(
      of, wproj_eff, b_proj, nullptr, nullptr, nullptr, (float*)d_out, 768, 768, 1);
}